// Round 4
// baseline (352.558 us; speedup 1.0000x reference)
//
#include <hip/hip_runtime.h>
#include <hip/hip_fp16.h>

#define NN 1024
#define MM 2048
#define NROWS 65536   // 16^4 rows per table

typedef float  f32x2 __attribute__((ext_vector_type(2)));

// ---------------------------------------------------------------------------
// Pass 1: convert the four f32 LUTs into packed fp16 rows (uint2 = 4 x half,
// 8 B each) in d_ws. Total 2 MiB -> L2-resident per XCD.
// ---------------------------------------------------------------------------
__global__ __launch_bounds__(256) void convert_lut_kernel(
    const float4* __restrict__ wh, const float4* __restrict__ wd,
    const float4* __restrict__ wt, const float4* __restrict__ wb,
    uint2* __restrict__ ws)
{
    int i = blockIdx.x * 256 + threadIdx.x;     // 0 .. 4*65536-1
    int t = i >> 16;
    int r = i & (NROWS - 1);
    const float4* src = (t == 0) ? wh : (t == 1) ? wd : (t == 2) ? wt : wb;
    float4 v = src[r];
    __half2 lo = __floats2half2_rn(v.x, v.y);
    __half2 hi = __floats2half2_rn(v.z, v.w);
    uint2 o;
    o.x = *reinterpret_cast<unsigned*>(&lo);
    o.y = *reinterpret_cast<unsigned*>(&hi);
    ws[i] = o;
}

__device__ __forceinline__ float2 h2f2(unsigned u) {
    __half2 h = *reinterpret_cast<__half2*>(&u);
    return __half22float2(h);
}

// ---------------------------------------------------------------------------
// Pass 2: fused 16-pass LUT upscaler. Structure: compute ALL 16 indices
// (LDS/VALU), then issue ALL 16 gathers back-to-back (MLP!), then reduce.
// Tap set (rotated-frame offsets):
// h: (0,0)(0,1)(0,2)(0,3)  d: (0,0)(1,1)(2,2)(3,3)
// t: (0,0)(2,1)(3,1)(3,2)  b: (0,0)(1,2)(1,3)(2,3)
// ---------------------------------------------------------------------------
__global__ __launch_bounds__(256, 4) void hdtb_lut_kernel(
    const int* __restrict__ img,
    const uint2* __restrict__ lut,   // [4][NROWS], order h,d,t,b
    float* __restrict__ out)
{
    const int b  = blockIdx.z;
    const int X0 = blockIdx.x * 32;
    const int Y0 = blockIdx.y * 8;
    const int tx = threadIdx.x, ty = threadIdx.y;
    const int X = X0 + tx, Y = Y0 + ty;

    // tile covers rows [Y0-3, Y0+10], cols [X0-3, X0+34]
    __shared__ unsigned char tile[14][40];

    const int* imgb = img + b * (NN * NN);
    int tid = ty * 32 + tx;
    for (int i = tid; i < 14 * 38; i += 256) {
        int r = i / 38, c = i - r * 38;
        int gy = Y0 - 3 + r;
        int gx = X0 - 3 + c;
        gy = gy < 0 ? 0 : (gy > NN - 1 ? NN - 1 : gy);   // clamped halo never read
        gx = gx < 0 ? 0 : (gx > NN - 1 ? NN - 1 : gx);
        tile[r][c] = (unsigned char)__builtin_nontemporal_load(&imgb[gy * NN + gx]);
    }
    __syncthreads();

    // Reflected coordinate arrays, tile-local.
    int ApL[4], AmL[4], BpL[4], BmL[4];
    #pragma unroll
    for (int t = 0; t < 4; ++t) {
        int ap = Y + t;              ap = ap < NN ? ap : 2 * NN - 2 - ap;
        int am = (NN - 1 - Y) + t;   am = am < NN ? am : 2 * NN - 2 - am;
        am = NN - 1 - am;
        int bp = X + t;              bp = bp < NN ? bp : 2 * NN - 2 - bp;
        int bm = (NN - 1 - X) + t;   bm = bm < NN ? bm : 2 * NN - 2 - bm;
        bm = NN - 1 - bm;
        ApL[t] = ap - (Y0 - 3);
        AmL[t] = am - (Y0 - 3);
        BpL[t] = bp - (X0 - 3);
        BmL[t] = bm - (X0 - 3);
    }

    // ---- Phase A: compute all 16 indices (no global loads yet) ----
#define MAKE_IDX(RA, CA, SW, IH, ID, IT, IB)                                      \
    {                                                                             \
        int v00, v01, v02, v03, v11, v22, v33, v21, v31, v32, v12, v13, v23;      \
        if (!(SW)) {                                                              \
            v00 = tile[RA[0]][CA[0]]; v01 = tile[RA[0]][CA[1]];                   \
            v02 = tile[RA[0]][CA[2]]; v03 = tile[RA[0]][CA[3]];                   \
            v11 = tile[RA[1]][CA[1]]; v22 = tile[RA[2]][CA[2]];                   \
            v33 = tile[RA[3]][CA[3]];                                             \
            v21 = tile[RA[2]][CA[1]]; v31 = tile[RA[3]][CA[1]];                   \
            v32 = tile[RA[3]][CA[2]];                                             \
            v12 = tile[RA[1]][CA[2]]; v13 = tile[RA[1]][CA[3]];                   \
            v23 = tile[RA[2]][CA[3]];                                             \
        } else { /* v[dy][dx] = tile[RA[dx]][CA[dy]] */                           \
            v00 = tile[RA[0]][CA[0]]; v01 = tile[RA[1]][CA[0]];                   \
            v02 = tile[RA[2]][CA[0]]; v03 = tile[RA[3]][CA[0]];                   \
            v11 = tile[RA[1]][CA[1]]; v22 = tile[RA[2]][CA[2]];                   \
            v33 = tile[RA[3]][CA[3]];                                             \
            v21 = tile[RA[1]][CA[2]]; v31 = tile[RA[1]][CA[3]];                   \
            v32 = tile[RA[2]][CA[3]];                                             \
            v12 = tile[RA[2]][CA[1]]; v13 = tile[RA[3]][CA[1]];                   \
            v23 = tile[RA[3]][CA[2]];                                             \
        }                                                                         \
        IH = ((v00 * 16 + v01) * 16 + v02) * 16 + v03;                            \
        ID = (((v00 * 16 + v11) * 16 + v22) * 16 + v33) + NROWS;                  \
        IT = (((v00 * 16 + v21) * 16 + v31) * 16 + v32) + 2 * NROWS;              \
        IB = (((v00 * 16 + v12) * 16 + v13) * 16 + v23) + 3 * NROWS;              \
    }

    int ih0, id0, it0, ib0, ih1, id1, it1, ib1;
    int ih2, id2, it2, ib2, ih3, id3, it3, ib3;
    MAKE_IDX(ApL, BpL, 0, ih0, id0, it0, ib0)   // r = 0
    MAKE_IDX(ApL, BmL, 1, ih1, id1, it1, ib1)   // r = 1
    MAKE_IDX(AmL, BmL, 0, ih2, id2, it2, ib2)   // r = 2
    MAKE_IDX(AmL, BpL, 1, ih3, id3, it3, ib3)   // r = 3
#undef MAKE_IDX

    // ---- Phase B: issue all 16 gathers back-to-back ----
    uint2 qh0 = lut[ih0], qd0 = lut[id0], qt0 = lut[it0], qb0 = lut[ib0];
    uint2 qh1 = lut[ih1], qd1 = lut[id1], qt1 = lut[it1], qb1 = lut[ib1];
    uint2 qh2 = lut[ih2], qd2 = lut[id2], qt2 = lut[it2], qb2 = lut[ib2];
    uint2 qh3 = lut[ih3], qd3 = lut[id3], qt3 = lut[it3], qb3 = lut[ib3];

    // ---- Phase C: convert + accumulate with per-rotation permutation ----
    float acc00 = 0.f, acc01 = 0.f, acc10 = 0.f, acc11 = 0.f;

#define ACCUM(Q0, Q1, Q2, Q3, A0, A1, A2, A3)                                     \
    {                                                                             \
        float2 x0 = h2f2(Q0.x), x1 = h2f2(Q1.x), x2 = h2f2(Q2.x), x3 = h2f2(Q3.x);\
        float2 y0 = h2f2(Q0.y), y1 = h2f2(Q1.y), y2 = h2f2(Q2.y), y3 = h2f2(Q3.y);\
        A0 += x0.x + x1.x + x2.x + x3.x;                                          \
        A1 += x0.y + x1.y + x2.y + x3.y;                                          \
        A2 += y0.x + y1.x + y2.x + y3.x;                                          \
        A3 += y0.y + y1.y + y2.y + y3.y;                                          \
    }
    ACCUM(qh0, qd0, qt0, qb0, acc00, acc01, acc10, acc11)   // r=0: s[p*2+q]
    ACCUM(qh1, qd1, qt1, qb1, acc01, acc11, acc00, acc10)   // r=1: acc[q][1-p]
    ACCUM(qh2, qd2, qt2, qb2, acc11, acc10, acc01, acc00)   // r=2: acc[1-p][1-q]
    ACCUM(qh3, qd3, qt3, qb3, acc10, acc00, acc11, acc01)   // r=3: acc[1-q][p]
#undef ACCUM

    size_t ob = (size_t)b * MM * MM;
    f32x2 top = { acc00 * 0.25f, acc01 * 0.25f };
    f32x2 bot = { acc10 * 0.25f, acc11 * 0.25f };
    __builtin_nontemporal_store(top,
        reinterpret_cast<f32x2*>(out + ob + (size_t)(2 * Y) * MM + 2 * X));
    __builtin_nontemporal_store(bot,
        reinterpret_cast<f32x2*>(out + ob + (size_t)(2 * Y + 1) * MM + 2 * X));
}

extern "C" void kernel_launch(void* const* d_in, const int* in_sizes, int n_in,
                              void* d_out, int out_size, void* d_ws, size_t ws_size,
                              hipStream_t stream) {
    const int*    img = (const int*)d_in[0];
    const float4* wh  = (const float4*)d_in[1];
    const float4* wd  = (const float4*)d_in[2];
    const float4* wt  = (const float4*)d_in[3];
    const float4* wb  = (const float4*)d_in[4];
    float* out = (float*)d_out;

    uint2* luth = (uint2*)d_ws;   // 4 tables x 65536 rows x 8 B = 2 MiB

    convert_lut_kernel<<<dim3(4 * NROWS / 256), dim3(256), 0, stream>>>(
        wh, wd, wt, wb, luth);

    dim3 block(32, 8, 1);
    dim3 grid(NN / 32, NN / 8, 4);
    hdtb_lut_kernel<<<grid, block, 0, stream>>>(img, luth, out);
}

// Round 5
// 348.400 us; speedup vs baseline: 1.0119x; 1.0119x over previous
//
#include <hip/hip_runtime.h>
#include <hip/hip_fp16.h>

#define NN 1024
#define MM 2048
#define NROWS 65536   // 16^4 rows per table

typedef float  f32x2 __attribute__((ext_vector_type(2)));

// ---------------------------------------------------------------------------
// Pass 1: convert the four f32 LUTs into packed fp16 rows (uint2 = 4 x half,
// 8 B each) in d_ws. Total 2 MiB -> L2-resident per XCD.
// ---------------------------------------------------------------------------
__global__ __launch_bounds__(256) void convert_lut_kernel(
    const float4* __restrict__ wh, const float4* __restrict__ wd,
    const float4* __restrict__ wt, const float4* __restrict__ wb,
    uint2* __restrict__ ws)
{
    int i = blockIdx.x * 256 + threadIdx.x;     // 0 .. 4*65536-1
    int t = i >> 16;
    int r = i & (NROWS - 1);
    const float4* src = (t == 0) ? wh : (t == 1) ? wd : (t == 2) ? wt : wb;
    float4 v = src[r];
    __half2 lo = __floats2half2_rn(v.x, v.y);
    __half2 hi = __floats2half2_rn(v.z, v.w);
    uint2 o;
    o.x = *reinterpret_cast<unsigned*>(&lo);
    o.y = *reinterpret_cast<unsigned*>(&hi);
    ws[i] = o;
}

__device__ __forceinline__ float2 h2f2(unsigned u) {
    __half2 h = *reinterpret_cast<__half2*>(&u);
    return __half22float2(h);
}

// ---------------------------------------------------------------------------
// Pass 2: fused 16-pass LUT upscaler. Phase A: all 16 indices (LDS/VALU).
// Phase B: all 16 gathers issued back-to-back, pinned by sched_barrier so the
// machine scheduler cannot re-serialize them against the consumers.
// Phase C: convert + accumulate (consumed in load order -> incremental vmcnt).
// Tap set (rotated-frame offsets):
// h: (0,0)(0,1)(0,2)(0,3)  d: (0,0)(1,1)(2,2)(3,3)
// t: (0,0)(2,1)(3,1)(3,2)  b: (0,0)(1,2)(1,3)(2,3)
// ---------------------------------------------------------------------------
__global__ __launch_bounds__(256, 4) void hdtb_lut_kernel(
    const int* __restrict__ img,
    const uint2* __restrict__ lut,   // [4][NROWS], order h,d,t,b
    float* __restrict__ out)
{
    const int b  = blockIdx.z;
    const int X0 = blockIdx.x * 32;
    const int Y0 = blockIdx.y * 8;
    const int tx = threadIdx.x, ty = threadIdx.y;
    const int X = X0 + tx, Y = Y0 + ty;

    // tile covers rows [Y0-3, Y0+10], cols [X0-3, X0+34]
    __shared__ unsigned char tile[14][40];

    const int* imgb = img + b * (NN * NN);
    int tid = ty * 32 + tx;
    for (int i = tid; i < 14 * 38; i += 256) {
        int r = i / 38, c = i - r * 38;
        int gy = Y0 - 3 + r;
        int gx = X0 - 3 + c;
        gy = gy < 0 ? 0 : (gy > NN - 1 ? NN - 1 : gy);   // clamped halo never read
        gx = gx < 0 ? 0 : (gx > NN - 1 ? NN - 1 : gx);
        tile[r][c] = (unsigned char)imgb[gy * NN + gx];
    }
    __syncthreads();

    // Reflected coordinate arrays, tile-local.
    int ApL[4], AmL[4], BpL[4], BmL[4];
    #pragma unroll
    for (int t = 0; t < 4; ++t) {
        int ap = Y + t;              ap = ap < NN ? ap : 2 * NN - 2 - ap;
        int am = (NN - 1 - Y) + t;   am = am < NN ? am : 2 * NN - 2 - am;
        am = NN - 1 - am;
        int bp = X + t;              bp = bp < NN ? bp : 2 * NN - 2 - bp;
        int bm = (NN - 1 - X) + t;   bm = bm < NN ? bm : 2 * NN - 2 - bm;
        bm = NN - 1 - bm;
        ApL[t] = ap - (Y0 - 3);
        AmL[t] = am - (Y0 - 3);
        BpL[t] = bp - (X0 - 3);
        BmL[t] = bm - (X0 - 3);
    }

    // ---- Phase A: compute all 16 indices (no global loads yet) ----
#define MAKE_IDX(RA, CA, SW, IH, ID, IT, IB)                                      \
    {                                                                             \
        int v00, v01, v02, v03, v11, v22, v33, v21, v31, v32, v12, v13, v23;      \
        if (!(SW)) {                                                              \
            v00 = tile[RA[0]][CA[0]]; v01 = tile[RA[0]][CA[1]];                   \
            v02 = tile[RA[0]][CA[2]]; v03 = tile[RA[0]][CA[3]];                   \
            v11 = tile[RA[1]][CA[1]]; v22 = tile[RA[2]][CA[2]];                   \
            v33 = tile[RA[3]][CA[3]];                                             \
            v21 = tile[RA[2]][CA[1]]; v31 = tile[RA[3]][CA[1]];                   \
            v32 = tile[RA[3]][CA[2]];                                             \
            v12 = tile[RA[1]][CA[2]]; v13 = tile[RA[1]][CA[3]];                   \
            v23 = tile[RA[2]][CA[3]];                                             \
        } else { /* v[dy][dx] = tile[RA[dx]][CA[dy]] */                           \
            v00 = tile[RA[0]][CA[0]]; v01 = tile[RA[1]][CA[0]];                   \
            v02 = tile[RA[2]][CA[0]]; v03 = tile[RA[3]][CA[0]];                   \
            v11 = tile[RA[1]][CA[1]]; v22 = tile[RA[2]][CA[2]];                   \
            v33 = tile[RA[3]][CA[3]];                                             \
            v21 = tile[RA[1]][CA[2]]; v31 = tile[RA[1]][CA[3]];                   \
            v32 = tile[RA[2]][CA[3]];                                             \
            v12 = tile[RA[2]][CA[1]]; v13 = tile[RA[3]][CA[1]];                   \
            v23 = tile[RA[3]][CA[2]];                                             \
        }                                                                         \
        IH = ((v00 * 16 + v01) * 16 + v02) * 16 + v03;                            \
        ID = (((v00 * 16 + v11) * 16 + v22) * 16 + v33) + NROWS;                  \
        IT = (((v00 * 16 + v21) * 16 + v31) * 16 + v32) + 2 * NROWS;              \
        IB = (((v00 * 16 + v12) * 16 + v13) * 16 + v23) + 3 * NROWS;              \
    }

    int ih0, id0, it0, ib0, ih1, id1, it1, ib1;
    int ih2, id2, it2, ib2, ih3, id3, it3, ib3;
    MAKE_IDX(ApL, BpL, 0, ih0, id0, it0, ib0)   // r = 0
    MAKE_IDX(ApL, BmL, 1, ih1, id1, it1, ib1)   // r = 1
    MAKE_IDX(AmL, BmL, 0, ih2, id2, it2, ib2)   // r = 2
    MAKE_IDX(AmL, BpL, 1, ih3, id3, it3, ib3)   // r = 3
#undef MAKE_IDX

    // ---- Phase B: issue ALL 16 gathers, fenced so none can sink past ----
    __builtin_amdgcn_sched_barrier(0);
    uint2 qh0 = lut[ih0], qd0 = lut[id0], qt0 = lut[it0], qb0 = lut[ib0];
    uint2 qh1 = lut[ih1], qd1 = lut[id1], qt1 = lut[it1], qb1 = lut[ib1];
    uint2 qh2 = lut[ih2], qd2 = lut[id2], qt2 = lut[it2], qb2 = lut[ib2];
    uint2 qh3 = lut[ih3], qd3 = lut[id3], qt3 = lut[it3], qb3 = lut[ib3];
    __builtin_amdgcn_sched_barrier(0);

    // ---- Phase C: convert + accumulate with per-rotation permutation ----
    float acc00 = 0.f, acc01 = 0.f, acc10 = 0.f, acc11 = 0.f;

#define ACCUM(Q0, Q1, Q2, Q3, A0, A1, A2, A3)                                     \
    {                                                                             \
        float2 x0 = h2f2(Q0.x), x1 = h2f2(Q1.x), x2 = h2f2(Q2.x), x3 = h2f2(Q3.x);\
        float2 y0 = h2f2(Q0.y), y1 = h2f2(Q1.y), y2 = h2f2(Q2.y), y3 = h2f2(Q3.y);\
        A0 += x0.x + x1.x + x2.x + x3.x;                                          \
        A1 += x0.y + x1.y + x2.y + x3.y;                                          \
        A2 += y0.x + y1.x + y2.x + y3.x;                                          \
        A3 += y0.y + y1.y + y2.y + y3.y;                                          \
    }
    ACCUM(qh0, qd0, qt0, qb0, acc00, acc01, acc10, acc11)   // r=0: s[p*2+q]
    ACCUM(qh1, qd1, qt1, qb1, acc01, acc11, acc00, acc10)   // r=1: acc[q][1-p]
    ACCUM(qh2, qd2, qt2, qb2, acc11, acc10, acc01, acc00)   // r=2: acc[1-p][1-q]
    ACCUM(qh3, qd3, qt3, qb3, acc10, acc00, acc11, acc01)   // r=3: acc[1-q][p]
#undef ACCUM

    size_t ob = (size_t)b * MM * MM;
    f32x2 top = { acc00 * 0.25f, acc01 * 0.25f };
    f32x2 bot = { acc10 * 0.25f, acc11 * 0.25f };
    __builtin_nontemporal_store(top,
        reinterpret_cast<f32x2*>(out + ob + (size_t)(2 * Y) * MM + 2 * X));
    __builtin_nontemporal_store(bot,
        reinterpret_cast<f32x2*>(out + ob + (size_t)(2 * Y + 1) * MM + 2 * X));
}

extern "C" void kernel_launch(void* const* d_in, const int* in_sizes, int n_in,
                              void* d_out, int out_size, void* d_ws, size_t ws_size,
                              hipStream_t stream) {
    const int*    img = (const int*)d_in[0];
    const float4* wh  = (const float4*)d_in[1];
    const float4* wd  = (const float4*)d_in[2];
    const float4* wt  = (const float4*)d_in[3];
    const float4* wb  = (const float4*)d_in[4];
    float* out = (float*)d_out;

    uint2* luth = (uint2*)d_ws;   // 4 tables x 65536 rows x 8 B = 2 MiB

    convert_lut_kernel<<<dim3(4 * NROWS / 256), dim3(256), 0, stream>>>(
        wh, wd, wt, wb, luth);

    dim3 block(32, 8, 1);
    dim3 grid(NN / 32, NN / 8, 4);
    hdtb_lut_kernel<<<grid, block, 0, stream>>>(img, luth, out);
}